// Round 1
// baseline (225.200 us; speedup 1.0000x reference)
//
#include <hip/hip_runtime.h>
#include <hip/hip_bf16.h>

// KAN layer fused as one augmented GEMM:
//   out[n][o] = sum_i silu(x[n][i])*scale_base[o][i]
//            + sum_{i,m} basis_m(x[n][i])*scale_sp[o][i]*coef[o][i][m] + bias[o]
// A_aug (8192 x 5376) f16, W_aug (768 x 5376) f16, k = j*768 + i (j=0: silu, j=1..6: basis)

typedef _Float16 f16;
typedef __attribute__((ext_vector_type(8))) _Float16 f16x8;
typedef __attribute__((ext_vector_type(4))) float f32x4;

#define NTOK 8192
#define DIN 768
#define DOUT 768
#define KAUG 5376   // 7*768
#define BM 128
#define BN 128
#define BK 32
#define KT (KAUG / BK)  // 168

typedef __attribute__((address_space(1))) void gvoid;
typedef __attribute__((address_space(3))) void lvoid;

// ---------------- Kernel 1: x -> [silu | 6 basis] f16 ----------------
__global__ __launch_bounds__(256) void build_A(const float* __restrict__ x,
                                               f16* __restrict__ Aa) {
  int idx = blockIdx.x * 256 + threadIdx.x;  // n*768 + i, exact grid
  float xv = x[idx];
  int n = idx / DIN;
  int i = idx - n * DIN;

  float s = xv / (1.0f + __expf(-xv));  // silu

  // Cox-de Boor, uniform extended grid t[g] = (g-3)*(2/3) - 1, g=0..9
  const float h = 2.0f / 3.0f;
  float B[9];
#pragma unroll
  for (int g = 0; g < 9; ++g) {
    float t0 = (float)(g - 3) * h - 1.0f;
    float t1 = (float)(g - 2) * h - 1.0f;
    B[g] = (xv >= t0 && xv < t1) ? 1.0f : 0.0f;
  }
#pragma unroll
  for (int p = 1; p <= 3; ++p) {
    float inv = 1.0f / ((float)p * h);
#pragma unroll
    for (int j = 0; j < 9 - 3; ++j) {  // only first 9-p matter; extra lanes harmless but keep exact
      if (j < 9 - p) {
        float tj = (float)(j - 3) * h - 1.0f;
        float tjp1 = (float)(j + p + 1 - 3) * h - 1.0f;
        B[j] = (xv - tj) * inv * B[j] + (tjp1 - xv) * inv * B[j + 1];
      }
    }
    // handle remaining indices j = 6..8-p for p<3 (needed by later levels)
#pragma unroll
    for (int j = 6; j < 9; ++j) {
      if (j < 9 - p) {
        float tj = (float)(j - 3) * h - 1.0f;
        float tjp1 = (float)(j + p + 1 - 3) * h - 1.0f;
        B[j] = (xv - tj) * inv * B[j] + (tjp1 - xv) * inv * B[j + 1];
      }
    }
  }

  size_t base = (size_t)n * KAUG + i;
  Aa[base] = (f16)s;
#pragma unroll
  for (int m = 0; m < 6; ++m) Aa[base + (size_t)(m + 1) * DIN] = (f16)B[m];
}

// ---------------- Kernel 2: pack weights ----------------
__global__ __launch_bounds__(256) void build_W(const float* __restrict__ sb,
                                               const float* __restrict__ ssp,
                                               const float* __restrict__ coef,
                                               f16* __restrict__ Wa) {
  int idx = blockIdx.x * 256 + threadIdx.x;  // o*768 + i, exact grid
  float b = sb[idx];
  float sp = ssp[idx];
  int o = idx / DIN;
  int i = idx - o * DIN;
  size_t base = (size_t)o * KAUG + i;
  Wa[base] = (f16)b;
#pragma unroll
  for (int m = 0; m < 6; ++m)
    Wa[base + (size_t)(m + 1) * DIN] = (f16)(sp * coef[(size_t)idx * 6 + m]);
}

// ---------------- Kernel 3: GEMM C = A_aug * W_aug^T + bias ----------------
// 128x128 tile, 4 waves (2x2 of 64x64), BK=32, global_load_lds width-16 staging.
__global__ __launch_bounds__(256) void kan_gemm(const f16* __restrict__ A,
                                                const f16* __restrict__ W,
                                                const float* __restrict__ bias,
                                                float* __restrict__ out) {
  __shared__ alignas(16) f16 As[BM * BK];  // 8 KB
  __shared__ alignas(16) f16 Bs[BN * BK];  // 8 KB

  const int tid = threadIdx.x;
  const int wave = tid >> 6;
  const int lane = tid & 63;
  const int m0 = blockIdx.y * BM;
  const int n0 = blockIdx.x * BN;
  const int wm = (wave >> 1) * 64;
  const int wn = (wave & 1) * 64;
  const int r = lane & 15;
  const int q = lane >> 4;

  f32x4 acc[4][4] = {};

  // staging chunk for instr s: c = s*256 + wave*64 + lane; row = c>>2, kblk = c&3
  const int c0 = wave * 64 + lane;
  const int rowA0 = c0 >> 2, kb0 = c0 & 3;
  const int c1 = c0 + 256;
  const int rowA1 = c1 >> 2, kb1 = c1 & 3;

  const f16* gA0 = A + (size_t)(m0 + rowA0) * KAUG + kb0 * 8;
  const f16* gA1 = A + (size_t)(m0 + rowA1) * KAUG + kb1 * 8;
  const f16* gB0 = W + (size_t)(n0 + rowA0) * KAUG + kb0 * 8;
  const f16* gB1 = W + (size_t)(n0 + rowA1) * KAUG + kb1 * 8;

  f16* ldsA = As + wave * 512;  // wave-uniform base (bytes: wave*1024)
  f16* ldsB = Bs + wave * 512;

  for (int kt = 0; kt < KT; ++kt) {
    const int koff = kt * BK;
    __builtin_amdgcn_global_load_lds((gvoid*)(gA0 + koff), (lvoid*)(ldsA), 16, 0, 0);
    __builtin_amdgcn_global_load_lds((gvoid*)(gA1 + koff), (lvoid*)(ldsA + 2048), 16, 0, 0);
    __builtin_amdgcn_global_load_lds((gvoid*)(gB0 + koff), (lvoid*)(ldsB), 16, 0, 0);
    __builtin_amdgcn_global_load_lds((gvoid*)(gB1 + koff), (lvoid*)(ldsB + 2048), 16, 0, 0);
    __syncthreads();  // compiler drains vmcnt(0) before s_barrier -> staging complete

    f16x8 af[4], bf[4];
#pragma unroll
    for (int mi = 0; mi < 4; ++mi)
      af[mi] = *(const f16x8*)&As[(wm + mi * 16 + r) * BK + q * 8];
#pragma unroll
    for (int ni = 0; ni < 4; ++ni)
      bf[ni] = *(const f16x8*)&Bs[(wn + ni * 16 + r) * BK + q * 8];
#pragma unroll
    for (int mi = 0; mi < 4; ++mi)
#pragma unroll
      for (int ni = 0; ni < 4; ++ni)
        acc[mi][ni] =
            __builtin_amdgcn_mfma_f32_16x16x32_f16(af[mi], bf[ni], acc[mi][ni], 0, 0, 0);
    __syncthreads();  // protect LDS before next iteration's staging
  }

  // epilogue: D mapping col = lane&15, row = q*4 + reg
#pragma unroll
  for (int mi = 0; mi < 4; ++mi) {
#pragma unroll
    for (int ni = 0; ni < 4; ++ni) {
      const int gcol = n0 + wn + ni * 16 + r;
      const float bv = bias[gcol];
#pragma unroll
      for (int rg = 0; rg < 4; ++rg) {
        const int grow = m0 + wm + mi * 16 + q * 4 + rg;
        out[(size_t)grow * DOUT + gcol] = acc[mi][ni][rg] + bv;
      }
    }
  }
}

extern "C" void kernel_launch(void* const* d_in, const int* in_sizes, int n_in,
                              void* d_out, int out_size, void* d_ws, size_t ws_size,
                              hipStream_t stream) {
  const float* x = (const float*)d_in[0];           // (4,2048,768)
  const float* coef = (const float*)d_in[1];        // (768,768,6)
  const float* scale_base = (const float*)d_in[2];  // (768,768)
  const float* scale_sp = (const float*)d_in[3];    // (768,768)
  const float* bias = (const float*)d_in[4];        // (768,)
  float* out = (float*)d_out;                       // (8192,768)

  f16* Aa = (f16*)d_ws;                                          // 8192*5376*2 = 88.1 MB
  f16* Wa = (f16*)((char*)d_ws + (size_t)NTOK * KAUG * 2);       // 768*5376*2  = 8.3 MB

  build_A<<<(NTOK * DIN) / 256, 256, 0, stream>>>(x, Aa);
  build_W<<<(DOUT * DIN) / 256, 256, 0, stream>>>(scale_base, scale_sp, coef, Wa);
  kan_gemm<<<dim3(DOUT / BN, NTOK / BM), 256, 0, stream>>>(Aa, Wa, bias, out);
}